// Round 8
// baseline (397.957 us; speedup 1.0000x reference)
//
#include <hip/hip_runtime.h>
#include <math.h>

#define NSPECIES 7
#define NRBF 16
#define SUBLEN 32
#define ROWLEN 1008      // 112 + 896
#define ANG_OFF 112
#define RADLEN 112
#define ANGLEN 896
#define M_ATOMS 24
#define APC 8            // atoms per block, angular kernel
#define MAXPAIR 276      // C(24,2)

typedef float v4f __attribute__((ext_vector_type(4)));

// ---------------- kA: triple records + boundary tables ----------------
__global__ void setup_kernel(const float* __restrict__ r_ij,
                             const int* __restrict__ pair_indices,
                             const int* __restrict__ species,
                             const int* __restrict__ close_idx,
                             const int* __restrict__ central_atom_index,
                             const int* __restrict__ pair_index12,
                             const int* __restrict__ sign12,
                             v4f* __restrict__ t_rec, int* __restrict__ t_dst,
                             int* __restrict__ pstart, int* __restrict__ tstart,
                             int P, int T, int nmol, int ngrp) {
    int t = blockIdx.x * blockDim.x + threadIdx.x;

    if (t <= P) {
        int m  = (t < P) ? pair_indices[t] / M_ATOMS : nmol;
        int mp = (t > 0) ? pair_indices[t - 1] / M_ATOMS : -1;
        for (int v = mp + 1; v <= m; ++v) pstart[v] = t;
    }
    if (t <= T) {
        int g  = (t < T) ? (central_atom_index[t] >> 3) : ngrp;
        int gp = (t > 0) ? (central_atom_index[t - 1] >> 3) : -1;
        for (int v = gp + 1; v <= g; ++v) tstart[v] = t;
    }
    if (t < T) {
        int p1 = pair_index12[t];
        int p2 = pair_index12[T + t];
        int s1 = sign12[t];
        int s2 = sign12[T + t];
        int ca = central_atom_index[t];
        int gp1 = close_idx[p1];
        int gp2 = close_idx[p2];

        float sg1 = (float)s1, sg2 = (float)s2;
        float v1x = r_ij[gp1 * 3 + 0] * sg1;
        float v1y = r_ij[gp1 * 3 + 1] * sg1;
        float v1z = r_ij[gp1 * 3 + 2] * sg1;
        float v2x = r_ij[gp2 * 3 + 0] * sg2;
        float v2y = r_ij[gp2 * 3 + 1] * sg2;
        float v2z = r_ij[gp2 * 3 + 2] * sg2;

        int spa = species[pair_indices[(s1 == 1 ? P : 0) + gp1]];
        int spb = species[pair_indices[(s2 == 1 ? P : 0) + gp2]];

        float d1 = sqrtf(v1x * v1x + v1y * v1y + v1z * v1z);
        float d2 = sqrtf(v2x * v2x + v2y * v2y + v2z * v2z);
        float dot = v1x * v2x + v1y * v2y + v1z * v2z;

        float cosang = 0.95f * dot / (d1 * d2);
        float sinang = sqrtf(fmaxf(1.0f - cosang * cosang, 0.0f));

        float fc1 = (d1 <= 0.35f) ? 0.5f * (__cosf(d1 * (float)(M_PI / 0.35)) + 1.0f) : 0.0f;
        float fc2 = (d2 <= 0.35f) ? 0.5f * (__cosf(d2 * (float)(M_PI / 0.35)) + 1.0f) : 0.0f;

        int lo = min(spa, spb), hi = max(spa, spb);
        int triu = lo * NSPECIES - (lo * (lo - 1)) / 2 + (hi - lo);

        v4f rec;
        rec.x = (d1 + d2) * 0.5f;
        rec.y = 2.0f * fc1 * fc2;
        rec.z = cosang;
        rec.w = sinang;
        t_rec[t] = rec;
        t_dst[t] = (ca << 5) | triu;
    }
}

// ---------------- kB: radial sections -> staging (ws), one block per molecule ----------------
__global__ __launch_bounds__(256) void radial_kernel(
        const float* __restrict__ d_ij,
        const int* __restrict__ pair_indices,
        const int* __restrict__ species,
        const int* __restrict__ pstart,
        float* __restrict__ outw, int P, int natoms) {
    __shared__ float rows[M_ATOMS * RADLEN];   // 10752 B
    __shared__ v4f stage[MAXPAIR];             // 4416 B

    int tid = threadIdx.x;
    int mol = blockIdx.x;
    int base = mol * M_ATOMS;
    if (base >= natoms) return;

    int p_lo = pstart[mol];
    int p_hi = pstart[mol + 1];
    int np = p_hi - p_lo;

    v4f z = {0.f, 0.f, 0.f, 0.f};
    v4f* r4 = (v4f*)rows;
    for (int c = tid; c < M_ATOMS * RADLEN / 4; c += 256) r4[c] = z;

    for (int k = tid; k < np; k += 256) {
        int p = p_lo + k;
        float d = d_ij[p];
        int i = pair_indices[p];
        int j = pair_indices[P + p];
        int si = species[i];
        int sj = species[j];
        float fc = (d <= 0.51f) ? 0.5f * (__cosf(d * (float)(M_PI / 0.51)) + 1.0f) : 0.0f;
        v4f s;
        s.x = d;
        s.y = 0.25f * fc;
        s.z = __int_as_float(((i - base) << 3) | sj);
        s.w = __int_as_float(((j - base) << 3) | si);
        stage[k] = s;
    }
    __syncthreads();

    int n16 = np * NRBF;
    for (int idx = tid; idx < n16; idx += 256) {
        int pp = idx >> 4;
        int k = idx & 15;
        v4f s = stage[pp];
        float shfr = 0.08f + (float)k * 0.026875f;
        float diff = s.x - shfr;
        float rfv = s.y * __expf(-1970.0f * diff * diff);
        int di = __float_as_int(s.z);
        int dj = __float_as_int(s.w);
        atomicAdd(&rows[(di >> 3) * RADLEN + (di & 7) * NRBF + k], rfv);
        atomicAdd(&rows[(dj >> 3) * RADLEN + (dj & 7) * NRBF + k], rfv);
    }
    __syncthreads();

    v4f* ov = (v4f*)outw;
    for (int c = tid; c < M_ATOMS * (RADLEN / 4); c += 256) {
        int r = c / (RADLEN / 4);
        int e = c % (RADLEN / 4);
        if (base + r < natoms) {
            ov[(size_t)(base + r) * (ROWLEN / 4) + e] = r4[c];
        }
    }
}

// ---------------- kC: angular sections -> staging (ws), one block per 8 atoms ----------------
__global__ __launch_bounds__(256) void angular_kernel(
        const v4f* __restrict__ t_rec, const int* __restrict__ t_dst,
        const int* __restrict__ tstart,
        float* __restrict__ outw, int natoms) {
    __shared__ float rows[APC * ANGLEN];   // 28672 B

    int tid = threadIdx.x;
    int grp = blockIdx.x;
    int base = grp * APC;
    if (base >= natoms) return;

    int t_lo = tstart[grp];
    int t_hi = tstart[grp + 1];

    v4f z = {0.f, 0.f, 0.f, 0.f};
    v4f* r4 = (v4f*)rows;
    for (int c = tid; c < APC * ANGLEN / 4; c += 256) r4[c] = z;
    __syncthreads();

    int n32 = (t_hi - t_lo) * SUBLEN;
    for (int idx = tid; idx < n32; idx += 256) {
        int t = t_lo + (idx >> 5);
        int l = idx & 31;

        v4f rec = t_rec[t];
        int dst = t_dst[t];

        int aa = l >> 2;
        int zz = l & 3;

        float shfa = 0.08f + (float)aa * 0.03375f;
        float dm = rec.x - shfa;
        float f2 = __expf(-800.0f * dm * dm);

        const float c8 = 0.92387953251f;   // cos(pi/8)
        const float s8 = 0.38268343236f;   // sin(pi/8)
        bool midz = (zz == 1) | (zz == 2);
        float cmag = midz ? s8 : c8;
        float smag = midz ? c8 : s8;
        float cz = (zz >= 2) ? -cmag : cmag;

        float bse = 0.5f * (1.0f + rec.z * cz + rec.w * smag);
        float x = bse * bse;  // ^2
        x = x * x;            // ^4
        x = x * x;            // ^8
        x = x * x;            // ^16
        x = x * x;            // ^32

        float term = rec.y * f2 * x;

        int row = (dst >> 5) - base;
        atomicAdd(&rows[row * ANGLEN + (dst & 31) * SUBLEN + l], term);
    }
    __syncthreads();

    v4f* ov = (v4f*)outw;
    for (int c = tid; c < APC * (ANGLEN / 4); c += 256) {
        int r = c / (ANGLEN / 4);
        int e = c % (ANGLEN / 4);
        if (base + r < natoms) {
            ov[(size_t)(base + r) * (ROWLEN / 4) + (ANG_OFF / 4) + e] = r4[c];
        }
    }
}

extern "C" void kernel_launch(void* const* d_in, const int* in_sizes, int n_in,
                              void* d_out, int out_size, void* d_ws, size_t ws_size,
                              hipStream_t stream) {
    const float* d_ij               = (const float*)d_in[0];
    const float* r_ij               = (const float*)d_in[1];
    const int*   pair_indices       = (const int*)d_in[2];
    const int*   species            = (const int*)d_in[3];
    const int*   close_idx          = (const int*)d_in[4];
    const int*   central_atom_index = (const int*)d_in[5];
    const int*   pair_index12       = (const int*)d_in[6];
    const int*   sign12             = (const int*)d_in[7];

    int P      = in_sizes[0];
    int T      = in_sizes[5];
    int natoms = in_sizes[3];
    int nmol   = natoms / M_ATOMS;         // 4000
    int ngrp   = (natoms + APC - 1) / APC; // 12000

    // workspace layout: full-output staging first (16B aligned), then records
    char* w = (char*)d_ws;
    float* outw = (float*)w;               w += (size_t)out_size * 4;
    v4f* t_rec  = (v4f*)w;                 w += (size_t)T * 16;
    int* t_dst  = (int*)w;                 w += (size_t)T * 4;
    int* pstart = (int*)w;                 w += (size_t)(nmol + 1) * 4;
    int* tstart = (int*)w;

    int n = max(P, T) + 1;
    setup_kernel<<<(n + 255) / 256, 256, 0, stream>>>(r_ij, pair_indices, species, close_idx,
                                                      central_atom_index, pair_index12, sign12,
                                                      t_rec, t_dst, pstart, tstart,
                                                      P, T, nmol, ngrp);
    radial_kernel<<<nmol, 256, 0, stream>>>(d_ij, pair_indices, species, pstart, outw, P, natoms);
    angular_kernel<<<ngrp, 256, 0, stream>>>(t_rec, t_dst, tstart, outw, natoms);

    // bulk staged result -> d_out via SDMA (different HW path than shader stores)
    hipMemcpyAsync(d_out, outw, (size_t)out_size * sizeof(float),
                   hipMemcpyDeviceToDevice, stream);
}

// Round 9
// 221.539 us; speedup vs baseline: 1.7963x; 1.7963x over previous
//
#include <hip/hip_runtime.h>
#include <math.h>

#define NSPECIES 7
#define NRBF 16
#define SUBLEN 32
#define ROWLEN 1008      // 112 + 896
#define ANG_OFF 112
#define M_ATOMS 24
#define APB 12           // atoms per block (half molecule)
#define THREADS 512
#define CH 224           // triple-record chunk (fits union stage)
#define MAXPAIR 280      // >= C(24,2) = 276

typedef float v4f __attribute__((ext_vector_type(4)));

// Boundary tables only: pstart[mol] over pair_indices[0] (sorted),
// tstart[12-atom block] over central_atom_index (sorted).
__global__ void table_kernel(const int* __restrict__ pair_indices,
                             const int* __restrict__ cai,
                             int* __restrict__ pstart, int* __restrict__ tstart,
                             int P, int T, int nmol, int nblk) {
    int t = blockIdx.x * blockDim.x + threadIdx.x;
    if (t <= P) {
        int m  = (t < P) ? pair_indices[t] / M_ATOMS : nmol;
        int mp = (t > 0) ? pair_indices[t - 1] / M_ATOMS : -1;
        for (int v = mp + 1; v <= m; ++v) pstart[v] = t;
    }
    if (t <= T) {
        int g  = (t < T) ? cai[t] / APB : nblk;
        int gp = (t > 0) ? cai[t - 1] / APB : -1;
        for (int v = gp + 1; v <= g; ++v) tstart[v] = t;
    }
}

// One block per 12 atoms: cooperative (non-redundant) record compute in LDS,
// LDS row accumulation, single contiguous 48KB nontemporal write.
__global__ __launch_bounds__(THREADS) void aev_fused(
        const float* __restrict__ d_ij,
        const float* __restrict__ r_ij,
        const int* __restrict__ pair_indices,
        const int* __restrict__ species,
        const int* __restrict__ close_idx,
        const int* __restrict__ cai,
        const int* __restrict__ pair_index12,
        const int* __restrict__ sign12,
        const int* __restrict__ pstart,
        const int* __restrict__ tstart,
        float* __restrict__ out, int P, int T, int natoms) {
    __shared__ float rows[APB * ROWLEN];                 // 48384 B
    __shared__ __align__(16) float ustage[MAXPAIR * 4];  // 4480 B, reused

    int tid = threadIdx.x;
    int blk = blockIdx.x;
    int base = blk * APB;
    if (base >= natoms) return;
    int mol = base / M_ATOMS;

    // zero rows
    v4f z = {0.f, 0.f, 0.f, 0.f};
    v4f* r4 = (v4f*)rows;
    for (int c = tid; c < APB * ROWLEN / 4; c += THREADS) r4[c] = z;

    int p_lo = pstart[mol], p_hi = pstart[mol + 1];
    int t_lo = tstart[blk], t_hi = tstart[blk + 1];
    int np = p_hi - p_lo;

    // ---- stage molecule's pairs once (cosf + gathers hoisted) ----
    v4f* pst = (v4f*)ustage;
    for (int k = tid; k < np; k += THREADS) {
        int p = p_lo + k;
        float d = d_ij[p];
        int i = pair_indices[p];
        int j = pair_indices[P + p];
        int si = species[i];
        int sj = species[j];
        float fc = (d <= 0.51f) ? 0.5f * (__cosf(d * (float)(M_PI / 0.51)) + 1.0f) : 0.0f;
        v4f s;
        s.x = d;
        s.y = 0.25f * fc;
        s.z = __int_as_float(((i - base) << 3) | sj);
        s.w = __int_as_float(((j - base) << 3) | si);
        pst[k] = s;
    }
    __syncthreads();

    // ---- radial expand (rows guarded to this block's 12 atoms) ----
    for (int idx = tid; idx < np * NRBF; idx += THREADS) {
        int pp = idx >> 4;
        int k = idx & 15;
        v4f s = pst[pp];
        float shfr = 0.08f + (float)k * 0.026875f;
        float diff = s.x - shfr;
        float rfv = s.y * __expf(-1970.0f * diff * diff);
        int di = __float_as_int(s.z);
        int dj = __float_as_int(s.w);
        int li = di >> 3, lj = dj >> 3;
        if ((unsigned)li < APB) atomicAdd(&rows[li * ROWLEN + (di & 7) * NRBF + k], rfv);
        if ((unsigned)lj < APB) atomicAdd(&rows[lj * ROWLEN + (dj & 7) * NRBF + k], rfv);
    }
    __syncthreads();   // ustage reuse barrier

    // ---- angular: chunks of CH triples; cooperative record compute ----
    v4f* trec = (v4f*)ustage;                 // floats [0, CH*4)
    int* tdst = ((int*)ustage) + CH * 4;      // ints  [CH*4, CH*5)

    for (int c0 = t_lo; c0 < t_hi; c0 += CH) {
        int n = min(CH, t_hi - c0);
        if (tid < n) {
            int t = c0 + tid;
            int p1 = pair_index12[t];
            int p2 = pair_index12[T + t];
            int s1 = sign12[t];
            int s2 = sign12[T + t];
            int ca = cai[t];
            int gp1 = close_idx[p1];
            int gp2 = close_idx[p2];

            float sg1 = (float)s1, sg2 = (float)s2;
            float v1x = r_ij[gp1 * 3 + 0] * sg1;
            float v1y = r_ij[gp1 * 3 + 1] * sg1;
            float v1z = r_ij[gp1 * 3 + 2] * sg1;
            float v2x = r_ij[gp2 * 3 + 0] * sg2;
            float v2y = r_ij[gp2 * 3 + 1] * sg2;
            float v2z = r_ij[gp2 * 3 + 2] * sg2;

            int spa = species[pair_indices[(s1 == 1 ? P : 0) + gp1]];
            int spb = species[pair_indices[(s2 == 1 ? P : 0) + gp2]];

            float d1 = sqrtf(v1x * v1x + v1y * v1y + v1z * v1z);
            float d2 = sqrtf(v2x * v2x + v2y * v2y + v2z * v2z);
            float dot = v1x * v2x + v1y * v2y + v1z * v2z;

            float cosang = 0.95f * dot / (d1 * d2);
            float sinang = sqrtf(fmaxf(1.0f - cosang * cosang, 0.0f));

            float fc1 = (d1 <= 0.35f) ? 0.5f * (__cosf(d1 * (float)(M_PI / 0.35)) + 1.0f) : 0.0f;
            float fc2 = (d2 <= 0.35f) ? 0.5f * (__cosf(d2 * (float)(M_PI / 0.35)) + 1.0f) : 0.0f;

            int lo = min(spa, spb), hi = max(spa, spb);
            int triu = lo * NSPECIES - (lo * (lo - 1)) / 2 + (hi - lo);

            v4f rec;
            rec.x = (d1 + d2) * 0.5f;
            rec.y = 2.0f * fc1 * fc2;
            rec.z = cosang;
            rec.w = sinang;
            trec[tid] = rec;
            tdst[tid] = ((ca - base) << 5) | triu;
        }
        __syncthreads();

        for (int idx = tid; idx < n * SUBLEN; idx += THREADS) {
            int tt = idx >> 5;
            int l = idx & 31;
            v4f rec = trec[tt];
            int dst = tdst[tt];

            int aa = l >> 2;
            int zz = l & 3;

            float shfa = 0.08f + (float)aa * 0.03375f;
            float dm = rec.x - shfa;
            float f2 = __expf(-800.0f * dm * dm);

            const float c8 = 0.92387953251f;   // cos(pi/8)
            const float s8 = 0.38268343236f;   // sin(pi/8)
            bool midz = (zz == 1) | (zz == 2);
            float cmag = midz ? s8 : c8;
            float smag = midz ? c8 : s8;
            float cz = (zz >= 2) ? -cmag : cmag;

            float bse = 0.5f * (1.0f + rec.z * cz + rec.w * smag);
            float x = bse * bse;  // ^2
            x = x * x;            // ^4
            x = x * x;            // ^8
            x = x * x;            // ^16
            x = x * x;            // ^32

            float term = rec.y * f2 * x;
            atomicAdd(&rows[(dst >> 5) * ROWLEN + ANG_OFF + (dst & 31) * SUBLEN + l], term);
        }
        __syncthreads();
    }

    // ---- one contiguous 48KB nontemporal write ----
    int nrows = min(APB, natoms - base);
    v4f* ov = (v4f*)(out + (size_t)base * ROWLEN);
    for (int c = tid; c < nrows * (ROWLEN / 4); c += THREADS) {
        v4f v = r4[c];
        __builtin_nontemporal_store(v, &ov[c]);
    }
}

extern "C" void kernel_launch(void* const* d_in, const int* in_sizes, int n_in,
                              void* d_out, int out_size, void* d_ws, size_t ws_size,
                              hipStream_t stream) {
    const float* d_ij               = (const float*)d_in[0];
    const float* r_ij               = (const float*)d_in[1];
    const int*   pair_indices       = (const int*)d_in[2];
    const int*   species            = (const int*)d_in[3];
    const int*   close_idx          = (const int*)d_in[4];
    const int*   central_atom_index = (const int*)d_in[5];
    const int*   pair_index12       = (const int*)d_in[6];
    const int*   sign12             = (const int*)d_in[7];
    float* out = (float*)d_out;

    int P      = in_sizes[0];
    int T      = in_sizes[5];
    int natoms = in_sizes[3];
    int nmol   = natoms / M_ATOMS;               // 4000
    int nblk   = (natoms + APB - 1) / APB;       // 8000

    // workspace: boundary tables only
    int* pstart = (int*)d_ws;
    int* tstart = pstart + (nmol + 1);

    int n = max(P, T) + 1;
    table_kernel<<<(n + 255) / 256, 256, 0, stream>>>(pair_indices, central_atom_index,
                                                      pstart, tstart, P, T, nmol, nblk);
    aev_fused<<<nblk, THREADS, 0, stream>>>(d_ij, r_ij, pair_indices, species, close_idx,
                                            central_atom_index, pair_index12, sign12,
                                            pstart, tstart, out, P, T, natoms);
}

// Round 10
// 215.003 us; speedup vs baseline: 1.8509x; 1.0304x over previous
//
#include <hip/hip_runtime.h>
#include <math.h>

#define NSPECIES 7
#define NRBF 16
#define SUBLEN 32
#define ROWLEN 1008      // 112 + 896
#define ANG_OFF 112
#define RADLEN 112
#define ANGLEN 896
#define M_ATOMS 24
#define APC 8            // atoms per block, angular kernel
#define MAXPAIR 276      // C(24,2)

typedef float v4f __attribute__((ext_vector_type(4)));

// ---------------- kA: triple records + boundary tables ----------------
// t_rec = {halfsum, 2*fc1*fc2, cosang, sinang}; t_dst = (ca<<5)|triu
// pstart[mol] / tstart[8-atom group] boundary tables from sorted inputs.
__global__ void setup_kernel(const float* __restrict__ r_ij,
                             const int* __restrict__ pair_indices,
                             const int* __restrict__ species,
                             const int* __restrict__ close_idx,
                             const int* __restrict__ central_atom_index,
                             const int* __restrict__ pair_index12,
                             const int* __restrict__ sign12,
                             v4f* __restrict__ t_rec, int* __restrict__ t_dst,
                             int* __restrict__ pstart, int* __restrict__ tstart,
                             int P, int T, int nmol, int ngrp) {
    int t = blockIdx.x * blockDim.x + threadIdx.x;

    if (t <= P) {
        int m  = (t < P) ? pair_indices[t] / M_ATOMS : nmol;
        int mp = (t > 0) ? pair_indices[t - 1] / M_ATOMS : -1;
        for (int v = mp + 1; v <= m; ++v) pstart[v] = t;
    }
    if (t <= T) {
        int g  = (t < T) ? (central_atom_index[t] >> 3) : ngrp;
        int gp = (t > 0) ? (central_atom_index[t - 1] >> 3) : -1;
        for (int v = gp + 1; v <= g; ++v) tstart[v] = t;
    }
    if (t < T) {
        int p1 = pair_index12[t];
        int p2 = pair_index12[T + t];
        int s1 = sign12[t];
        int s2 = sign12[T + t];
        int ca = central_atom_index[t];
        int gp1 = close_idx[p1];
        int gp2 = close_idx[p2];

        float sg1 = (float)s1, sg2 = (float)s2;
        float v1x = r_ij[gp1 * 3 + 0] * sg1;
        float v1y = r_ij[gp1 * 3 + 1] * sg1;
        float v1z = r_ij[gp1 * 3 + 2] * sg1;
        float v2x = r_ij[gp2 * 3 + 0] * sg2;
        float v2y = r_ij[gp2 * 3 + 1] * sg2;
        float v2z = r_ij[gp2 * 3 + 2] * sg2;

        int spa = species[pair_indices[(s1 == 1 ? P : 0) + gp1]];
        int spb = species[pair_indices[(s2 == 1 ? P : 0) + gp2]];

        float d1 = sqrtf(v1x * v1x + v1y * v1y + v1z * v1z);
        float d2 = sqrtf(v2x * v2x + v2y * v2y + v2z * v2z);
        float dot = v1x * v2x + v1y * v2y + v1z * v2z;

        float cosang = 0.95f * dot / (d1 * d2);
        float sinang = sqrtf(fmaxf(1.0f - cosang * cosang, 0.0f));

        float fc1 = (d1 <= 0.35f) ? 0.5f * (__cosf(d1 * (float)(M_PI / 0.35)) + 1.0f) : 0.0f;
        float fc2 = (d2 <= 0.35f) ? 0.5f * (__cosf(d2 * (float)(M_PI / 0.35)) + 1.0f) : 0.0f;

        int lo = min(spa, spb), hi = max(spa, spb);
        int triu = lo * NSPECIES - (lo * (lo - 1)) / 2 + (hi - lo);

        v4f rec;
        rec.x = (d1 + d2) * 0.5f;
        rec.y = 2.0f * fc1 * fc2;
        rec.z = cosang;
        rec.w = sinang;
        t_rec[t] = rec;
        t_dst[t] = (ca << 5) | triu;
    }
}

// ---------------- kB: radial sections, one block per molecule ----------------
__global__ __launch_bounds__(256) void radial_kernel(
        const float* __restrict__ d_ij,
        const int* __restrict__ pair_indices,
        const int* __restrict__ species,
        const int* __restrict__ pstart,
        float* __restrict__ out, int P, int natoms) {
    __shared__ float rows[M_ATOMS * RADLEN];   // 10752 B
    __shared__ v4f stage[MAXPAIR];             // 4416 B

    int tid = threadIdx.x;
    int mol = blockIdx.x;
    int base = mol * M_ATOMS;
    if (base >= natoms) return;

    int p_lo = pstart[mol];
    int p_hi = pstart[mol + 1];
    int np = p_hi - p_lo;

    v4f z = {0.f, 0.f, 0.f, 0.f};
    v4f* r4 = (v4f*)rows;
    for (int c = tid; c < M_ATOMS * RADLEN / 4; c += 256) r4[c] = z;

    // stage per-pair values once (cosf + gathers hoisted out of the x16 loop)
    for (int k = tid; k < np; k += 256) {
        int p = p_lo + k;
        float d = d_ij[p];
        int i = pair_indices[p];
        int j = pair_indices[P + p];
        int si = species[i];
        int sj = species[j];
        float fc = (d <= 0.51f) ? 0.5f * (__cosf(d * (float)(M_PI / 0.51)) + 1.0f) : 0.0f;
        v4f s;
        s.x = d;
        s.y = 0.25f * fc;
        s.z = __int_as_float(((i - base) << 3) | sj);
        s.w = __int_as_float(((j - base) << 3) | si);
        stage[k] = s;
    }
    __syncthreads();

    int n16 = np * NRBF;
    for (int idx = tid; idx < n16; idx += 256) {
        int pp = idx >> 4;
        int k = idx & 15;
        v4f s = stage[pp];
        float shfr = 0.08f + (float)k * 0.026875f;
        float diff = s.x - shfr;
        float rfv = s.y * __expf(-1970.0f * diff * diff);
        int di = __float_as_int(s.z);
        int dj = __float_as_int(s.w);
        atomicAdd(&rows[(di >> 3) * RADLEN + (di & 7) * NRBF + k], rfv);
        atomicAdd(&rows[(dj >> 3) * RADLEN + (dj & 7) * NRBF + k], rfv);
    }
    __syncthreads();

    // write 24 rows x 112 floats (28 v4f each) at ROWLEN stride
    v4f* ov = (v4f*)out;
    for (int c = tid; c < M_ATOMS * (RADLEN / 4); c += 256) {
        int r = c / (RADLEN / 4);
        int e = c % (RADLEN / 4);
        if (base + r < natoms) {
            v4f v = r4[c];
            __builtin_nontemporal_store(v, &ov[(size_t)(base + r) * (ROWLEN / 4) + e]);
        }
    }
}

// ---------------- kC: angular sections, one block per 8 atoms ----------------
__global__ __launch_bounds__(256) void angular_kernel(
        const v4f* __restrict__ t_rec, const int* __restrict__ t_dst,
        const int* __restrict__ tstart,
        float* __restrict__ out, int natoms) {
    __shared__ float rows[APC * ANGLEN];   // 28672 B

    int tid = threadIdx.x;
    int grp = blockIdx.x;
    int base = grp * APC;
    if (base >= natoms) return;

    int t_lo = tstart[grp];
    int t_hi = tstart[grp + 1];

    v4f z = {0.f, 0.f, 0.f, 0.f};
    v4f* r4 = (v4f*)rows;
    for (int c = tid; c < APC * ANGLEN / 4; c += 256) r4[c] = z;
    __syncthreads();

    int n32 = (t_hi - t_lo) * SUBLEN;
    for (int idx = tid; idx < n32; idx += 256) {
        int t = t_lo + (idx >> 5);
        int l = idx & 31;

        v4f rec = t_rec[t];
        int dst = t_dst[t];

        int aa = l >> 2;
        int zz = l & 3;

        float shfa = 0.08f + (float)aa * 0.03375f;
        float dm = rec.x - shfa;
        float f2 = __expf(-800.0f * dm * dm);

        const float c8 = 0.92387953251f;   // cos(pi/8)
        const float s8 = 0.38268343236f;   // sin(pi/8)
        bool midz = (zz == 1) | (zz == 2);
        float cmag = midz ? s8 : c8;
        float smag = midz ? c8 : s8;
        float cz = (zz >= 2) ? -cmag : cmag;

        float bse = 0.5f * (1.0f + rec.z * cz + rec.w * smag);
        float x = bse * bse;  // ^2
        x = x * x;            // ^4
        x = x * x;            // ^8
        x = x * x;            // ^16
        x = x * x;            // ^32

        float term = rec.y * f2 * x;

        int row = (dst >> 5) - base;
        atomicAdd(&rows[row * ANGLEN + (dst & 31) * SUBLEN + l], term);
    }
    __syncthreads();

    // write 8 rows x 896 floats (224 v4f each) at ROWLEN stride, +ANG_OFF
    v4f* ov = (v4f*)out;
    for (int c = tid; c < APC * (ANGLEN / 4); c += 256) {
        int r = c / (ANGLEN / 4);
        int e = c % (ANGLEN / 4);
        if (base + r < natoms) {
            v4f v = r4[c];
            __builtin_nontemporal_store(v, &ov[(size_t)(base + r) * (ROWLEN / 4) + (ANG_OFF / 4) + e]);
        }
    }
}

extern "C" void kernel_launch(void* const* d_in, const int* in_sizes, int n_in,
                              void* d_out, int out_size, void* d_ws, size_t ws_size,
                              hipStream_t stream) {
    const float* d_ij               = (const float*)d_in[0];
    const float* r_ij               = (const float*)d_in[1];
    const int*   pair_indices       = (const int*)d_in[2];
    const int*   species            = (const int*)d_in[3];
    const int*   close_idx          = (const int*)d_in[4];
    const int*   central_atom_index = (const int*)d_in[5];
    const int*   pair_index12       = (const int*)d_in[6];
    const int*   sign12             = (const int*)d_in[7];
    float* out = (float*)d_out;

    int P      = in_sizes[0];
    int T      = in_sizes[5];
    int natoms = in_sizes[3];
    int nmol   = natoms / M_ATOMS;        // 4000
    int ngrp   = (natoms + APC - 1) / APC; // 12000

    // workspace layout (t_rec first for 16B alignment)
    char* w = (char*)d_ws;
    v4f* t_rec  = (v4f*)w;                 w += (size_t)T * 16;
    int* t_dst  = (int*)w;                 w += (size_t)T * 4;
    int* pstart = (int*)w;                 w += (size_t)(nmol + 1) * 4;
    int* tstart = (int*)w;

    int n = max(P, T) + 1;
    setup_kernel<<<(n + 255) / 256, 256, 0, stream>>>(r_ij, pair_indices, species, close_idx,
                                                      central_atom_index, pair_index12, sign12,
                                                      t_rec, t_dst, pstart, tstart,
                                                      P, T, nmol, ngrp);
    radial_kernel<<<nmol, 256, 0, stream>>>(d_ij, pair_indices, species, pstart, out, P, natoms);
    angular_kernel<<<ngrp, 256, 0, stream>>>(t_rec, t_dst, tstart, out, natoms);
}